// Round 7
// baseline (440.718 us; speedup 1.0000x reference)
//
#include <hip/hip_runtime.h>
#include <hip/hip_fp16.h>

#define NN 50000
#define EE 800000
#define ENE (EE + NN)   // edges + self loops

typedef _Float16 f16;
typedef __attribute__((ext_vector_type(8))) _Float16 f16x8;
typedef __attribute__((ext_vector_type(4))) _Float16 f16x4;
typedef __attribute__((ext_vector_type(4))) float f32x4;

// ---------------------------------------------------------------------------
// CSR build: degree count -> exclusive scan -> scatter (bump allocator).
// After scatter, offs[n] = end of segment n; beg(n) = n ? offs[n-1] : 0.
// ---------------------------------------------------------------------------

__global__ __launch_bounds__(256)
void deg_kernel(const int* __restrict__ ei, int* __restrict__ deg) {
    int i = blockIdx.x * 256 + threadIdx.x;
    if (i >= ENE) return;
    int d = (i < EE) ? ei[EE + i] : (i - EE);   // dst row of edge_index
    atomicAdd(&deg[d], 1);
}

__global__ __launch_bounds__(1024)
void scan1_kernel(const int* __restrict__ deg, int* __restrict__ offs,
                  int* __restrict__ bsum) {
    __shared__ int s[1024];
    int t = threadIdx.x;
    int i = blockIdx.x * 1024 + t;
    int v = (i < NN) ? deg[i] : 0;
    s[t] = v;
    __syncthreads();
    for (int off = 1; off < 1024; off <<= 1) {
        int a = (t >= off) ? s[t - off] : 0;
        __syncthreads();
        s[t] += a;
        __syncthreads();
    }
    if (i < NN) offs[i] = s[t] - v;   // exclusive
    if (t == 1023) bsum[blockIdx.x] = s[1023];
}

__global__ __launch_bounds__(64)
void scan2_kernel(const int* __restrict__ bsum, int* __restrict__ bpre, int nb) {
    if (threadIdx.x == 0) {
        int run = 0;
        for (int b = 0; b < nb; ++b) { bpre[b] = run; run += bsum[b]; }
    }
}

__global__ __launch_bounds__(256)
void scan3_kernel(int* __restrict__ offs, const int* __restrict__ bpre) {
    int i = blockIdx.x * 256 + threadIdx.x;
    if (i >= NN) return;
    offs[i] += bpre[i >> 10];
}

__global__ __launch_bounds__(256)
void scatter_kernel(const int* __restrict__ ei, int* __restrict__ offs,
                    int* __restrict__ csr_src, int* __restrict__ csr_dst) {
    int i = blockIdx.x * 256 + threadIdx.x;
    if (i >= ENE) return;
    int d, s;
    if (i < EE) { s = ei[i]; d = ei[EE + i]; }
    else        { s = i - EE; d = i - EE; }
    int p = atomicAdd(&offs[d], 1);
    csr_src[p] = s;
    csr_dst[p] = d;
}

// ---------------------------------------------------------------------------
// fp32 weights -> transposed fp16 copies (MFMA B-fragments = contiguous 16B).
// ---------------------------------------------------------------------------

__global__ __launch_bounds__(256)
void cast_w_kernel(const float* __restrict__ W1, const float* __restrict__ W2,
                   const float* __restrict__ Wm1, f16* __restrict__ W1t,
                   f16* __restrict__ W2t, f16* __restrict__ Wmt) {
    int idx = blockIdx.x * 256 + threadIdx.x;
    if (idx < 32768) {                       // W1t[j*128+k] = W1[k*256+j]
        int j = idx >> 7, k = idx & 127;
        W1t[idx] = (f16)W1[k * 256 + j];
    } else if (idx < 49152) {                // W2t[j*256+k] = W2[k*64+j]
        int i = idx - 32768;
        int j = i >> 8, k = i & 255;
        W2t[i] = (f16)W2[k * 64 + j];
    } else if (idx < 57344) {                // Wmt[j*64+k]
        int i = idx - 49152;
        int j = i >> 6, k = i & 63;
        float v = (j < 64) ? Wm1[k * 64 + j] : Wm1[(64 + k) * 64 + (j - 64)];
        Wmt[i] = (f16)v;
    }
}

// ---------------------------------------------------------------------------
// MFMA fp16 GEMM: Yh[n, NOUT] = A[n, K] @ Bt^T   (Bt is [NOUT][K] fp16)
// 4 waves/block; wave (wr,wc) computes 16 rows x 64 cols via 4x
// v_mfma_f32_16x16x32_f16 per k-step, register-direct fragments.
// PERM=1: permuted [n][c(64)][h(4)] output layout.
// AF32=1: A is fp32, converted in-register.
// SCORES=1: fused layer-1 attention scores. SCORES=2: fused layer-2 scores.
// ---------------------------------------------------------------------------

template<int K, int NOUT, int NWR, int NWC, int PERM, int AF32, int SCORES>
__global__ __launch_bounds__(256)
void mfma_gemm(const void* __restrict__ Avoid, const f16* __restrict__ Bt,
               f16* __restrict__ Yh, const float* __restrict__ a_src,
               const float* __restrict__ a_dst, float* __restrict__ ss,
               float* __restrict__ sd, int nrows) {
    constexpr int BROWS = NWR * 16;
    constexpr int LDP = NOUT + 8;            // halves per LDS row (16B pad)
    __shared__ f16 lds[BROWS * LDP];
    const int tid = threadIdx.x;
    const int wid = tid >> 6, lane = tid & 63;
    const int wr = wid / NWC, wc = wid % NWC;
    const int lm = lane & 15, lk = lane >> 4;      // lk in 0..3
    const int row0 = blockIdx.x * BROWS + wr * 16;
    const int col0 = wc * 64;

    const float* A32 = (const float*)Avoid;
    const f16*   A16 = (const f16*)Avoid;

    int arow = row0 + lm;
    if (arow >= nrows) arow = nrows - 1;           // clamp (partial last block)

    f32x4 acc[4] = {};
#pragma unroll
    for (int ks = 0; ks < K / 32; ++ks) {
        f16x8 af;
        if (AF32) {
            float4 v0 = *(const float4*)&A32[(size_t)arow * K + ks * 32 + lk * 8];
            float4 v1 = *(const float4*)&A32[(size_t)arow * K + ks * 32 + lk * 8 + 4];
            af = f16x8{(f16)v0.x, (f16)v0.y, (f16)v0.z, (f16)v0.w,
                       (f16)v1.x, (f16)v1.y, (f16)v1.z, (f16)v1.w};
        } else {
            af = *(const f16x8*)(A16 + (size_t)arow * K + ks * 32 + lk * 8);
        }
#pragma unroll
        for (int ct = 0; ct < 4; ++ct) {
            const f16* bptr = Bt + (size_t)(col0 + ct * 16 + lm) * K + ks * 32 + lk * 8;
            f16x8 bf = *(const f16x8*)bptr;
            acc[ct] = __builtin_amdgcn_mfma_f32_16x16x32_f16(af, bf, acc[ct], 0, 0, 0);
        }
    }

    // C/D frag: col = lane&15, row = (lane>>4)*4 + r  [m89 layout]
#pragma unroll
    for (int ct = 0; ct < 4; ++ct) {
#pragma unroll
        for (int r = 0; r < 4; ++r) {
            int lrow = wr * 16 + lk * 4 + r;       // local row in block
            int j = col0 + ct * 16 + lm;           // global col
            int jj = PERM ? ((j & 63) * 4 + (j >> 6)) : j;
            lds[lrow * LDP + jj] = (f16)acc[ct][r];
        }
    }
    __syncthreads();

    constexpr int CHUNKS = NOUT / 8;               // 16B chunks per row
    for (int idx = tid; idx < BROWS * CHUNKS; idx += 256) {
        int lrow = idx / CHUNKS, ch = idx % CHUNKS;
        int grow = blockIdx.x * BROWS + lrow;
        if (grow < nrows) {
            f16x8 v = *(const f16x8*)&lds[lrow * LDP + ch * 8];
            *(f16x8*)&Yh[(size_t)grow * NOUT + ch * 8] = v;
        }
    }

    if (SCORES == 1) {
        // layer-1: ss[n][h] = sum_c h[n,h,c]*a_src[h,c]; lds is [16][c*4+h].
        int rloc = wid * 4 + (lane >> 4);
        int ci = lane & 15;
        float ps[4] = {}, pd[4] = {};
#pragma unroll
        for (int cc = 0; cc < 4; ++cc) {
            int c = ci + cc * 16;
            f16x4 hv = *(const f16x4*)&lds[rloc * LDP + c * 4];
#pragma unroll
            for (int h = 0; h < 4; ++h) {
                float f = (float)hv[h];
                ps[h] += f * a_src[h * 64 + c];
                pd[h] += f * a_dst[h * 64 + c];
            }
        }
#pragma unroll
        for (int m = 1; m < 16; m <<= 1) {
#pragma unroll
            for (int h = 0; h < 4; ++h) {
                ps[h] += __shfl_xor(ps[h], m);
                pd[h] += __shfl_xor(pd[h], m);
            }
        }
        if (ci == 0) {
            int grow = blockIdx.x * BROWS + rloc;
            if (grow < nrows) {
                *(float4*)&ss[grow * 4] = make_float4(ps[0], ps[1], ps[2], ps[3]);
                *(float4*)&sd[grow * 4] = make_float4(pd[0], pd[1], pd[2], pd[3]);
            }
        }
    } else if (SCORES == 2) {
        // layer-2: ss[n] = sum_c h2[n,c]*a_src[c]; 4 lanes/row, 16 c's each.
        int rloc = wid * 16 + (lane >> 2);
        int cg = lane & 3;
        float ps = 0.f, pd = 0.f;
#pragma unroll
        for (int b = 0; b < 2; ++b) {
            f16x8 hv = *(const f16x8*)&lds[rloc * LDP + cg * 16 + b * 8];
#pragma unroll
            for (int u = 0; u < 8; ++u) {
                int c = cg * 16 + b * 8 + u;
                float f = (float)hv[u];
                ps += f * a_src[c];
                pd += f * a_dst[c];
            }
        }
        ps += __shfl_xor(ps, 1); ps += __shfl_xor(ps, 2);
        pd += __shfl_xor(pd, 1); pd += __shfl_xor(pd, 2);
        if (cg == 0) {
            int grow = blockIdx.x * BROWS + rloc;
            if (grow < nrows) { ss[grow] = ps; sd[grow] = pd; }
        }
    }
}

// ---------------------------------------------------------------------------
// Per-edge (CSR-slot-ordered) unnormalized softmax weights.
// ---------------------------------------------------------------------------

__global__ __launch_bounds__(256)
void p1_kernel(const int* __restrict__ csr_src, const int* __restrict__ csr_dst,
               const float* __restrict__ ss, const float* __restrict__ sd,
               float4* __restrict__ p1) {
    int j = blockIdx.x * 256 + threadIdx.x;
    if (j >= ENE) return;
    int s = csr_src[j], d = csr_dst[j];
    float4 a = *(const float4*)&ss[s * 4];
    float4 b = *(const float4*)&sd[d * 4];
    float e0 = a.x + b.x; e0 = e0 > 0.f ? e0 : 0.2f * e0;
    float e1 = a.y + b.y; e1 = e1 > 0.f ? e1 : 0.2f * e1;
    float e2 = a.z + b.z; e2 = e2 > 0.f ? e2 : 0.2f * e2;
    float e3 = a.w + b.w; e3 = e3 > 0.f ? e3 : 0.2f * e3;
    p1[j] = make_float4(__expf(e0), __expf(e1), __expf(e2), __expf(e3));
}

__global__ __launch_bounds__(256)
void p2_kernel(const int* __restrict__ csr_src, const int* __restrict__ csr_dst,
               const float* __restrict__ ss, const float* __restrict__ sd,
               float* __restrict__ p2) {
    int j = blockIdx.x * 256 + threadIdx.x;
    if (j >= ENE) return;
    float e = ss[csr_src[j]] + sd[csr_dst[j]];
    e = e > 0.f ? e : 0.2f * e;
    p2[j] = __expf(e);
}

// ---------------------------------------------------------------------------
// Layer-1 aggregation: TWO waves per dst node (each takes half the edge list,
// unroll-4 inside), partials combined via LDS. lane = channel, fp16 gather.
// Block = 256 thr = 4 waves = 2 nodes. NN even -> no boundary divergence.
// ---------------------------------------------------------------------------

__global__ __launch_bounds__(256)
void agg1_kernel(const int* __restrict__ offs, const int* __restrict__ csr_src,
                 const float4* __restrict__ p1, const f16* __restrict__ h1h,
                 const float* __restrict__ b1, f16* __restrict__ h1half) {
    __shared__ float part[2][8][64];
    int lane = threadIdx.x & 63;
    int wid = threadIdx.x >> 6;
    int ni = wid >> 1;          // node slot in block
    int hw = wid & 1;           // which half of the edge list
    int n = blockIdx.x * 2 + ni;            // grid = NN/2 exactly
    int beg = (n == 0) ? 0 : offs[n - 1];
    int end = offs[n];
    int half = (end - beg) >> 1;
    int b0 = hw ? (beg + half) : beg;
    int e0 = hw ? end : (beg + half);

    float den0 = 0.f, den1 = 0.f, den2 = 0.f, den3 = 0.f;
    float ac0 = 0.f, ac1 = 0.f, ac2 = 0.f, ac3 = 0.f;
    int j = b0;
    for (; j + 4 <= e0; j += 4) {
        int s0 = csr_src[j + 0];
        int s1 = csr_src[j + 1];
        int s2 = csr_src[j + 2];
        int s3 = csr_src[j + 3];
        float4 q0 = p1[j + 0];
        float4 q1 = p1[j + 1];
        float4 q2 = p1[j + 2];
        float4 q3 = p1[j + 3];
        f16x4 h0 = *(const f16x4*)&h1h[(size_t)s0 * 256 + lane * 4];
        f16x4 h1 = *(const f16x4*)&h1h[(size_t)s1 * 256 + lane * 4];
        f16x4 h2 = *(const f16x4*)&h1h[(size_t)s2 * 256 + lane * 4];
        f16x4 h3 = *(const f16x4*)&h1h[(size_t)s3 * 256 + lane * 4];
        den0 += (q0.x + q1.x) + (q2.x + q3.x);
        den1 += (q0.y + q1.y) + (q2.y + q3.y);
        den2 += (q0.z + q1.z) + (q2.z + q3.z);
        den3 += (q0.w + q1.w) + (q2.w + q3.w);
        ac0 += q0.x * (float)h0[0] + q1.x * (float)h1[0]
             + q2.x * (float)h2[0] + q3.x * (float)h3[0];
        ac1 += q0.y * (float)h0[1] + q1.y * (float)h1[1]
             + q2.y * (float)h2[1] + q3.y * (float)h3[1];
        ac2 += q0.z * (float)h0[2] + q1.z * (float)h1[2]
             + q2.z * (float)h2[2] + q3.z * (float)h3[2];
        ac3 += q0.w * (float)h0[3] + q1.w * (float)h1[3]
             + q2.w * (float)h2[3] + q3.w * (float)h3[3];
    }
    for (; j < e0; ++j) {
        int s = csr_src[j];
        float4 pv = p1[j];
        f16x4 hv = *(const f16x4*)&h1h[(size_t)s * 256 + lane * 4];
        den0 += pv.x; den1 += pv.y; den2 += pv.z; den3 += pv.w;
        ac0 += pv.x * (float)hv[0];
        ac1 += pv.y * (float)hv[1];
        ac2 += pv.z * (float)hv[2];
        ac3 += pv.w * (float)hv[3];
    }

    if (hw == 1) {
        part[ni][0][lane] = den0; part[ni][1][lane] = den1;
        part[ni][2][lane] = den2; part[ni][3][lane] = den3;
        part[ni][4][lane] = ac0;  part[ni][5][lane] = ac1;
        part[ni][6][lane] = ac2;  part[ni][7][lane] = ac3;
    }
    __syncthreads();
    if (hw == 0) {
        den0 += part[ni][0][lane]; den1 += part[ni][1][lane];
        den2 += part[ni][2][lane]; den3 += part[ni][3][lane];
        ac0  += part[ni][4][lane]; ac1  += part[ni][5][lane];
        ac2  += part[ni][6][lane]; ac3  += part[ni][7][lane];
        float r0 = ac0 / (den0 + 1e-16f) + b1[lane];
        float r1 = ac1 / (den1 + 1e-16f) + b1[64 + lane];
        float r2 = ac2 / (den2 + 1e-16f) + b1[128 + lane];
        float r3 = ac3 / (den3 + 1e-16f) + b1[192 + lane];
        f16* orow = &h1half[(size_t)n * 256];
        orow[lane]       = (f16)(r0 > 0.f ? r0 : 0.f);
        orow[64 + lane]  = (f16)(r1 > 0.f ? r1 : 0.f);
        orow[128 + lane] = (f16)(r2 > 0.f ? r2 : 0.f);
        orow[192 + lane] = (f16)(r3 > 0.f ? r3 : 0.f);
    }
}

// Layer-2 aggregation: same 2-wave-per-node split, 1 head.
__global__ __launch_bounds__(256)
void agg2_kernel(const int* __restrict__ offs, const int* __restrict__ csr_src,
                 const float* __restrict__ p2, const f16* __restrict__ h2linh,
                 const float* __restrict__ b2, f16* __restrict__ h2half) {
    __shared__ float part[2][2][64];
    int lane = threadIdx.x & 63;
    int wid = threadIdx.x >> 6;
    int ni = wid >> 1;
    int hw = wid & 1;
    int n = blockIdx.x * 2 + ni;
    int beg = (n == 0) ? 0 : offs[n - 1];
    int end = offs[n];
    int half = (end - beg) >> 1;
    int b0 = hw ? (beg + half) : beg;
    int e0 = hw ? end : (beg + half);

    float den = 0.f, acc = 0.f;
    int j = b0;
    for (; j + 4 <= e0; j += 4) {
        int s0 = csr_src[j + 0];
        int s1 = csr_src[j + 1];
        int s2 = csr_src[j + 2];
        int s3 = csr_src[j + 3];
        float q0 = p2[j + 0];
        float q1 = p2[j + 1];
        float q2 = p2[j + 2];
        float q3 = p2[j + 3];
        float v0 = (float)h2linh[(size_t)s0 * 64 + lane];
        float v1 = (float)h2linh[(size_t)s1 * 64 + lane];
        float v2 = (float)h2linh[(size_t)s2 * 64 + lane];
        float v3 = (float)h2linh[(size_t)s3 * 64 + lane];
        den += (q0 + q1) + (q2 + q3);
        acc += q0 * v0 + q1 * v1 + q2 * v2 + q3 * v3;
    }
    for (; j < e0; ++j) {
        int s = csr_src[j];
        float p = p2[j];
        den += p;
        acc += p * (float)h2linh[(size_t)s * 64 + lane];
    }

    if (hw == 1) {
        part[ni][0][lane] = den;
        part[ni][1][lane] = acc;
    }
    __syncthreads();
    if (hw == 0) {
        den += part[ni][0][lane];
        acc += part[ni][1][lane];
        h2half[(size_t)n * 64 + lane] = (f16)(acc / (den + 1e-16f) + b2[lane]);
    }
}

// ---------------------------------------------------------------------------
// Edge epilogue: z = relu(g_top[p] + g_bot[c] + bm1); out = z @ Wm2 + bm2
// 16 lanes per edge; gh is fp16 [n][128].
// ---------------------------------------------------------------------------

__global__ __launch_bounds__(256)
void edge_kernel(const int* __restrict__ ei, const f16* __restrict__ gh,
                 const float* __restrict__ bm1, const float* __restrict__ Wm2,
                 const float* __restrict__ bm2, float* __restrict__ out) {
    int l = threadIdx.x & 15;
    int eid = blockIdx.x * 16 + (threadIdx.x >> 4);
    if (eid >= EE) return;
    int p = ei[eid];
    int c = ei[EE + eid];
    f16x4 av = *(const f16x4*)&gh[(size_t)p * 128 + l * 4];
    f16x4 bv = *(const f16x4*)&gh[(size_t)c * 128 + 64 + l * 4];
    float4 bb = *(const float4*)&bm1[l * 4];
    float zx = (float)av[0] + (float)bv[0] + bb.x; zx = zx > 0.f ? zx : 0.f;
    float zy = (float)av[1] + (float)bv[1] + bb.y; zy = zy > 0.f ? zy : 0.f;
    float zz = (float)av[2] + (float)bv[2] + bb.z; zz = zz > 0.f ? zz : 0.f;
    float zw = (float)av[3] + (float)bv[3] + bb.w; zw = zw > 0.f ? zw : 0.f;
    float4 w01 = *(const float4*)&Wm2[l * 8];       // rows 4l, 4l+1
    float4 w23 = *(const float4*)&Wm2[l * 8 + 4];   // rows 4l+2, 4l+3
    float o0 = zx * w01.x + zy * w01.z + zz * w23.x + zw * w23.z;
    float o1 = zx * w01.y + zy * w01.w + zz * w23.y + zw * w23.w;
#pragma unroll
    for (int m = 1; m < 16; m <<= 1) {
        o0 += __shfl_xor(o0, m);
        o1 += __shfl_xor(o1, m);
    }
    if (l == 0)
        *(float2*)&out[(size_t)eid * 2] = make_float2(o0 + bm2[0], o1 + bm2[1]);
}

// ---------------------------------------------------------------------------

extern "C" void kernel_launch(void* const* d_in, const int* in_sizes, int n_in,
                              void* d_out, int out_size, void* d_ws, size_t ws_size,
                              hipStream_t stream) {
    const float* x      = (const float*)d_in[0];
    const int*   ei     = (const int*)d_in[1];
    const float* W1     = (const float*)d_in[2];
    const float* a_src1 = (const float*)d_in[3];
    const float* a_dst1 = (const float*)d_in[4];
    const float* b1     = (const float*)d_in[5];
    const float* W2     = (const float*)d_in[6];
    const float* a_src2 = (const float*)d_in[7];
    const float* a_dst2 = (const float*)d_in[8];
    const float* b2     = (const float*)d_in[9];
    const float* Wm1    = (const float*)d_in[10];
    const float* bm1    = (const float*)d_in[11];
    const float* Wm2    = (const float*)d_in[12];
    const float* bm2    = (const float*)d_in[13];
    float* out = (float*)d_out;

    char* ws = (char*)d_ws;
    size_t off = 0;
    auto alloc = [&](size_t bytes) -> void* {
        void* p = ws + off;
        off += (bytes + 255) & ~(size_t)255;
        return p;
    };
    int*    deg     = (int*)alloc((size_t)NN * 4);
    int*    offs    = (int*)alloc((size_t)NN * 4);
    int*    bsum    = (int*)alloc(64 * 4);
    int*    bpre    = (int*)alloc(64 * 4);
    int*    csr_src = (int*)alloc((size_t)ENE * 4);
    int*    csr_dst = (int*)alloc((size_t)ENE * 4);
    float*  ss1     = (float*)alloc((size_t)NN * 4 * 4);
    float*  sd1     = (float*)alloc((size_t)NN * 4 * 4);
    float*  ss2     = (float*)alloc((size_t)NN * 4);
    float*  sd2     = (float*)alloc((size_t)NN * 4);
    float4* p1      = (float4*)alloc((size_t)ENE * 16);
    float*  p2      = (float*)alloc((size_t)ENE * 4);
    f16*    W1t     = (f16*)alloc((size_t)256 * 128 * 2);
    f16*    W2t     = (f16*)alloc((size_t)64 * 256 * 2);
    f16*    Wmt     = (f16*)alloc((size_t)128 * 64 * 2);
    f16*    h1h     = (f16*)alloc((size_t)NN * 256 * 2);   // permuted [n][c][h]
    f16*    h1half  = (f16*)alloc((size_t)NN * 256 * 2);   // [n][h*64+c]
    f16*    h2linh  = (f16*)alloc((size_t)NN * 64 * 2);
    f16*    h2half  = (f16*)alloc((size_t)NN * 64 * 2);
    f16*    gh      = (f16*)alloc((size_t)NN * 128 * 2);
    if (off > ws_size) return;   // insufficient workspace: leave output poisoned

    const int nbScan  = (NN + 1023) / 1024;        // 49
    const int gEdges  = (ENE + 255) / 256;         // 3321
    const int gNodes2 = NN / 2;                    // 25000 (2 waves/node)
    const int gEdge16 = (EE + 15) / 16;            // 50000

    // Weight casts (independent of CSR)
    cast_w_kernel<<<(57344 + 255) / 256, 256, 0, stream>>>(W1, W2, Wm1, W1t, W2t, Wmt);

    // CSR build
    hipMemsetAsync(deg, 0, (size_t)NN * 4, stream);
    deg_kernel<<<gEdges, 256, 0, stream>>>(ei, deg);
    scan1_kernel<<<nbScan, 1024, 0, stream>>>(deg, offs, bsum);
    scan2_kernel<<<1, 64, 0, stream>>>(bsum, bpre, nbScan);
    scan3_kernel<<<(NN + 255) / 256, 256, 0, stream>>>(offs, bpre);
    scatter_kernel<<<gEdges, 256, 0, stream>>>(ei, offs, csr_src, csr_dst);

    // Layer 1: h1h = fp16( x @ W1 ), permuted epilogue + fused scores
    mfma_gemm<128, 256, 1, 4, 1, 1, 1><<<NN / 16, 256, 0, stream>>>(
        x, W1t, h1h, a_src1, a_dst1, ss1, sd1, NN);
    p1_kernel<<<gEdges, 256, 0, stream>>>(csr_src, csr_dst, ss1, sd1, p1);
    agg1_kernel<<<gNodes2, 256, 0, stream>>>(offs, csr_src, p1, h1h, b1, h1half);

    // Layer 2: h2lin = h1 @ W2 (+ fused scores)
    mfma_gemm<256, 64, 4, 1, 0, 0, 2><<<(NN + 63) / 64, 256, 0, stream>>>(
        h1half, W2t, h2linh, a_src2, a_dst2, ss2, sd2, NN);
    p2_kernel<<<gEdges, 256, 0, stream>>>(csr_src, csr_dst, ss2, sd2, p2);
    agg2_kernel<<<gNodes2, 256, 0, stream>>>(offs, csr_src, p2, h2linh, b2, h2half);

    // Edge MLP (factorized): gh = h2 @ [Wm1_top | Wm1_bot], per-edge epilogue
    mfma_gemm<64, 128, 2, 2, 0, 0, 0><<<(NN + 31) / 32, 256, 0, stream>>>(
        h2half, Wmt, gh, nullptr, nullptr, nullptr, nullptr, NN);
    edge_kernel<<<gEdge16, 256, 0, stream>>>(ei, gh, bm1, Wm2, bm2, out);
}

// Round 10
// 406.809 us; speedup vs baseline: 1.0834x; 1.0834x over previous
//
#include <hip/hip_runtime.h>
#include <hip/hip_fp16.h>

#define NN 50000
#define EE 800000
#define ENE (EE + NN)   // edges + self loops

typedef _Float16 f16;
typedef __attribute__((ext_vector_type(8))) _Float16 f16x8;
typedef __attribute__((ext_vector_type(4))) _Float16 f16x4;
typedef __attribute__((ext_vector_type(2))) _Float16 f16x2;
typedef __attribute__((ext_vector_type(4))) float f32x4;

// ---------------------------------------------------------------------------
// CSR build: degree count -> exclusive scan -> scatter (bump allocator).
// After scatter, offs[n] = end of segment n; beg(n) = n ? offs[n-1] : 0.
// ---------------------------------------------------------------------------

__global__ __launch_bounds__(256)
void deg_kernel(const int* __restrict__ ei, int* __restrict__ deg) {
    int i = blockIdx.x * 256 + threadIdx.x;
    if (i >= ENE) return;
    int d = (i < EE) ? ei[EE + i] : (i - EE);   // dst row of edge_index
    atomicAdd(&deg[d], 1);
}

__global__ __launch_bounds__(1024)
void scan1_kernel(const int* __restrict__ deg, int* __restrict__ offs,
                  int* __restrict__ bsum) {
    __shared__ int s[1024];
    int t = threadIdx.x;
    int i = blockIdx.x * 1024 + t;
    int v = (i < NN) ? deg[i] : 0;
    s[t] = v;
    __syncthreads();
    for (int off = 1; off < 1024; off <<= 1) {
        int a = (t >= off) ? s[t - off] : 0;
        __syncthreads();
        s[t] += a;
        __syncthreads();
    }
    if (i < NN) offs[i] = s[t] - v;   // exclusive
    if (t == 1023) bsum[blockIdx.x] = s[1023];
}

__global__ __launch_bounds__(64)
void scan2_kernel(const int* __restrict__ bsum, int* __restrict__ bpre, int nb) {
    if (threadIdx.x == 0) {
        int run = 0;
        for (int b = 0; b < nb; ++b) { bpre[b] = run; run += bsum[b]; }
    }
}

__global__ __launch_bounds__(256)
void scan3_kernel(int* __restrict__ offs, const int* __restrict__ bpre) {
    int i = blockIdx.x * 256 + threadIdx.x;
    if (i >= NN) return;
    offs[i] += bpre[i >> 10];
}

// Scatter + fused layer-1 edge weights: p1[slot] = exp(leaky(ss1[s]+sd1[d])).
// Runs after gemm1 (needs ss1/sd1).
__global__ __launch_bounds__(256)
void scatter_p1_kernel(const int* __restrict__ ei, int* __restrict__ offs,
                       int* __restrict__ csr_src, int* __restrict__ csr_dst,
                       const float* __restrict__ ss, const float* __restrict__ sd,
                       float4* __restrict__ p1) {
    int i = blockIdx.x * 256 + threadIdx.x;
    if (i >= ENE) return;
    int d, s;
    if (i < EE) { s = ei[i]; d = ei[EE + i]; }
    else        { s = i - EE; d = i - EE; }
    int slot = atomicAdd(&offs[d], 1);
    csr_src[slot] = s;
    csr_dst[slot] = d;
    float4 a = *(const float4*)&ss[s * 4];
    float4 b = *(const float4*)&sd[d * 4];
    float e0 = a.x + b.x; e0 = e0 > 0.f ? e0 : 0.2f * e0;
    float e1 = a.y + b.y; e1 = e1 > 0.f ? e1 : 0.2f * e1;
    float e2 = a.z + b.z; e2 = e2 > 0.f ? e2 : 0.2f * e2;
    float e3 = a.w + b.w; e3 = e3 > 0.f ? e3 : 0.2f * e3;
    p1[slot] = make_float4(__expf(e0), __expf(e1), __expf(e2), __expf(e3));
}

// ---------------------------------------------------------------------------
// fp32 weights -> transposed fp16 copies (MFMA B-fragments = contiguous 16B).
// ---------------------------------------------------------------------------

__global__ __launch_bounds__(256)
void cast_w_kernel(const float* __restrict__ W1, const float* __restrict__ W2,
                   const float* __restrict__ Wm1, f16* __restrict__ W1t,
                   f16* __restrict__ W2t, f16* __restrict__ Wmt) {
    int idx = blockIdx.x * 256 + threadIdx.x;
    if (idx < 32768) {                       // W1t[j*128+k] = W1[k*256+j]
        int j = idx >> 7, k = idx & 127;
        W1t[idx] = (f16)W1[k * 256 + j];
    } else if (idx < 49152) {                // W2t[j*256+k] = W2[k*64+j]
        int i = idx - 32768;
        int j = i >> 8, k = i & 255;
        W2t[i] = (f16)W2[k * 64 + j];
    } else if (idx < 57344) {                // Wmt[j*64+k]
        int i = idx - 49152;
        int j = i >> 6, k = i & 63;
        float v = (j < 64) ? Wm1[k * 64 + j] : Wm1[(64 + k) * 64 + (j - 64)];
        Wmt[i] = (f16)v;
    }
}

// ---------------------------------------------------------------------------
// MFMA fp16 GEMM: Yh[n, NOUT] = A[n, K] @ Bt^T   (Bt is [NOUT][K] fp16)
// 4 waves/block; wave (wr,wc) computes 16 rows x 64 cols via 4x
// v_mfma_f32_16x16x32_f16 per k-step, register-direct fragments.
// PERM=1: permuted [n][c(64)][h(4)] output layout.
// AF32=1: A is fp32, converted in-register.
// SCORES=1: fused layer-1 attention scores. SCORES=2: fused layer-2 scores.
// ---------------------------------------------------------------------------

template<int K, int NOUT, int NWR, int NWC, int PERM, int AF32, int SCORES>
__global__ __launch_bounds__(256)
void mfma_gemm(const void* __restrict__ Avoid, const f16* __restrict__ Bt,
               f16* __restrict__ Yh, const float* __restrict__ a_src,
               const float* __restrict__ a_dst, float* __restrict__ ss,
               float* __restrict__ sd, int nrows) {
    constexpr int BROWS = NWR * 16;
    constexpr int LDP = NOUT + 8;            // halves per LDS row (16B pad)
    __shared__ f16 lds[BROWS * LDP];
    const int tid = threadIdx.x;
    const int wid = tid >> 6, lane = tid & 63;
    const int wr = wid / NWC, wc = wid % NWC;
    const int lm = lane & 15, lk = lane >> 4;      // lk in 0..3
    const int row0 = blockIdx.x * BROWS + wr * 16;
    const int col0 = wc * 64;

    const float* A32 = (const float*)Avoid;
    const f16*   A16 = (const f16*)Avoid;

    int arow = row0 + lm;
    if (arow >= nrows) arow = nrows - 1;           // clamp (partial last block)

    f32x4 acc[4] = {};
#pragma unroll
    for (int ks = 0; ks < K / 32; ++ks) {
        f16x8 af;
        if (AF32) {
            float4 v0 = *(const float4*)&A32[(size_t)arow * K + ks * 32 + lk * 8];
            float4 v1 = *(const float4*)&A32[(size_t)arow * K + ks * 32 + lk * 8 + 4];
            af = f16x8{(f16)v0.x, (f16)v0.y, (f16)v0.z, (f16)v0.w,
                       (f16)v1.x, (f16)v1.y, (f16)v1.z, (f16)v1.w};
        } else {
            af = *(const f16x8*)(A16 + (size_t)arow * K + ks * 32 + lk * 8);
        }
#pragma unroll
        for (int ct = 0; ct < 4; ++ct) {
            const f16* bptr = Bt + (size_t)(col0 + ct * 16 + lm) * K + ks * 32 + lk * 8;
            f16x8 bf = *(const f16x8*)bptr;
            acc[ct] = __builtin_amdgcn_mfma_f32_16x16x32_f16(af, bf, acc[ct], 0, 0, 0);
        }
    }

    // C/D frag: col = lane&15, row = (lane>>4)*4 + r  [m89 layout]
#pragma unroll
    for (int ct = 0; ct < 4; ++ct) {
#pragma unroll
        for (int r = 0; r < 4; ++r) {
            int lrow = wr * 16 + lk * 4 + r;       // local row in block
            int j = col0 + ct * 16 + lm;           // global col
            int jj = PERM ? ((j & 63) * 4 + (j >> 6)) : j;
            lds[lrow * LDP + jj] = (f16)acc[ct][r];
        }
    }
    __syncthreads();

    constexpr int CHUNKS = NOUT / 8;               // 16B chunks per row
    for (int idx = tid; idx < BROWS * CHUNKS; idx += 256) {
        int lrow = idx / CHUNKS, ch = idx % CHUNKS;
        int grow = blockIdx.x * BROWS + lrow;
        if (grow < nrows) {
            f16x8 v = *(const f16x8*)&lds[lrow * LDP + ch * 8];
            *(f16x8*)&Yh[(size_t)grow * NOUT + ch * 8] = v;
        }
    }

    if (SCORES == 1) {
        // layer-1: ss[n][h] = sum_c h[n,h,c]*a_src[h,c]; lds is [16][c*4+h].
        int rloc = wid * 4 + (lane >> 4);
        int ci = lane & 15;
        float ps[4] = {}, pd[4] = {};
#pragma unroll
        for (int cc = 0; cc < 4; ++cc) {
            int c = ci + cc * 16;
            f16x4 hv = *(const f16x4*)&lds[rloc * LDP + c * 4];
#pragma unroll
            for (int h = 0; h < 4; ++h) {
                float f = (float)hv[h];
                ps[h] += f * a_src[h * 64 + c];
                pd[h] += f * a_dst[h * 64 + c];
            }
        }
#pragma unroll
        for (int m = 1; m < 16; m <<= 1) {
#pragma unroll
            for (int h = 0; h < 4; ++h) {
                ps[h] += __shfl_xor(ps[h], m);
                pd[h] += __shfl_xor(pd[h], m);
            }
        }
        if (ci == 0) {
            int grow = blockIdx.x * BROWS + rloc;
            if (grow < nrows) {
                *(float4*)&ss[grow * 4] = make_float4(ps[0], ps[1], ps[2], ps[3]);
                *(float4*)&sd[grow * 4] = make_float4(pd[0], pd[1], pd[2], pd[3]);
            }
        }
    } else if (SCORES == 2) {
        // layer-2: ss[n] = sum_c h2[n,c]*a_src[c]; 4 lanes/row, 16 c's each.
        int rloc = wid * 16 + (lane >> 2);
        int cg = lane & 3;
        float ps = 0.f, pd = 0.f;
#pragma unroll
        for (int b = 0; b < 2; ++b) {
            f16x8 hv = *(const f16x8*)&lds[rloc * LDP + cg * 16 + b * 8];
#pragma unroll
            for (int u = 0; u < 8; ++u) {
                int c = cg * 16 + b * 8 + u;
                float f = (float)hv[u];
                ps += f * a_src[c];
                pd += f * a_dst[c];
            }
        }
        ps += __shfl_xor(ps, 1); ps += __shfl_xor(ps, 2);
        pd += __shfl_xor(pd, 1); pd += __shfl_xor(pd, 2);
        if (cg == 0) {
            int grow = blockIdx.x * BROWS + rloc;
            if (grow < nrows) { ss[grow] = ps; sd[grow] = pd; }
        }
    }
}

// ---------------------------------------------------------------------------
// Layer-2 per-edge weights (CSR-slot-ordered).
// ---------------------------------------------------------------------------

__global__ __launch_bounds__(256)
void p2_kernel(const int* __restrict__ csr_src, const int* __restrict__ csr_dst,
               const float* __restrict__ ss, const float* __restrict__ sd,
               float* __restrict__ p2) {
    int j = blockIdx.x * 256 + threadIdx.x;
    if (j >= ENE) return;
    float e = ss[csr_src[j]] + sd[csr_dst[j]];
    e = e > 0.f ? e : 0.2f * e;
    p2[j] = __expf(e);
}

// ---------------------------------------------------------------------------
// Layer-1 aggregation: ONE wave per dst node; intra-wave edge PAIRING:
// lanes 0-31 take even CSR slots, lanes 32-63 odd slots (interleaved -> csr/p
// loads for the pair are contiguous). Lane l covers channels 2l,2l+1 x 4 heads
// via one 16B load. Halves combined by shfl_xor(...,32). Unroll-4 on top.
// ---------------------------------------------------------------------------

__global__ __launch_bounds__(256)
void agg1_kernel(const int* __restrict__ offs, const int* __restrict__ csr_src,
                 const float4* __restrict__ p1, const f16* __restrict__ h1h,
                 const float* __restrict__ b1, f16* __restrict__ h1half) {
    int lane = threadIdx.x & 63;
    int hw = lane >> 5;         // which edge of the pair
    int l = lane & 31;          // channel pair index
    int n = blockIdx.x * 4 + (threadIdx.x >> 6);
    if (n >= NN) return;
    int beg = (n == 0) ? 0 : offs[n - 1];
    int end = offs[n];

    float den0 = 0.f, den1 = 0.f, den2 = 0.f, den3 = 0.f;
    float aA0 = 0.f, aA1 = 0.f, aA2 = 0.f, aA3 = 0.f;   // channel 2l
    float aB0 = 0.f, aB1 = 0.f, aB2 = 0.f, aB3 = 0.f;   // channel 2l+1
    int j = beg + hw;           // stride-2 walk per half

#define AGG1_BODY(JJ)                                                          \
    {                                                                          \
        int s_ = csr_src[JJ];                                                  \
        float4 q_ = p1[JJ];                                                    \
        f16x8 hv_ = *(const f16x8*)&h1h[(size_t)s_ * 256 + l * 8];             \
        den0 += q_.x; den1 += q_.y; den2 += q_.z; den3 += q_.w;                \
        aA0 += q_.x * (float)hv_[0]; aB0 += q_.x * (float)hv_[4];              \
        aA1 += q_.y * (float)hv_[1]; aB1 += q_.y * (float)hv_[5];              \
        aA2 += q_.z * (float)hv_[2]; aB2 += q_.z * (float)hv_[6];              \
        aA3 += q_.w * (float)hv_[3]; aB3 += q_.w * (float)hv_[7];              \
    }

    for (; j + 6 < end; j += 8) {
        int s0 = csr_src[j + 0];
        int s1 = csr_src[j + 2];
        int s2 = csr_src[j + 4];
        int s3 = csr_src[j + 6];
        float4 q0 = p1[j + 0];
        float4 q1 = p1[j + 2];
        float4 q2 = p1[j + 4];
        float4 q3 = p1[j + 6];
        f16x8 h0 = *(const f16x8*)&h1h[(size_t)s0 * 256 + l * 8];
        f16x8 h1v = *(const f16x8*)&h1h[(size_t)s1 * 256 + l * 8];
        f16x8 h2v = *(const f16x8*)&h1h[(size_t)s2 * 256 + l * 8];
        f16x8 h3v = *(const f16x8*)&h1h[(size_t)s3 * 256 + l * 8];
        den0 += (q0.x + q1.x) + (q2.x + q3.x);
        den1 += (q0.y + q1.y) + (q2.y + q3.y);
        den2 += (q0.z + q1.z) + (q2.z + q3.z);
        den3 += (q0.w + q1.w) + (q2.w + q3.w);
        aA0 += q0.x * (float)h0[0] + q1.x * (float)h1v[0]
             + q2.x * (float)h2v[0] + q3.x * (float)h3v[0];
        aB0 += q0.x * (float)h0[4] + q1.x * (float)h1v[4]
             + q2.x * (float)h2v[4] + q3.x * (float)h3v[4];
        aA1 += q0.y * (float)h0[1] + q1.y * (float)h1v[1]
             + q2.y * (float)h2v[1] + q3.y * (float)h3v[1];
        aB1 += q0.y * (float)h0[5] + q1.y * (float)h1v[5]
             + q2.y * (float)h2v[5] + q3.y * (float)h3v[5];
        aA2 += q0.z * (float)h0[2] + q1.z * (float)h1v[2]
             + q2.z * (float)h2v[2] + q3.z * (float)h3v[2];
        aB2 += q0.z * (float)h0[6] + q1.z * (float)h1v[6]
             + q2.z * (float)h2v[6] + q3.z * (float)h3v[6];
        aA3 += q0.w * (float)h0[3] + q1.w * (float)h1v[3]
             + q2.w * (float)h2v[3] + q3.w * (float)h3v[3];
        aB3 += q0.w * (float)h0[7] + q1.w * (float)h1v[7]
             + q2.w * (float)h2v[7] + q3.w * (float)h3v[7];
    }
    for (; j < end; j += 2) AGG1_BODY(j);
#undef AGG1_BODY

    // combine the two halves (edge-pair partials)
    den0 += __shfl_xor(den0, 32); den1 += __shfl_xor(den1, 32);
    den2 += __shfl_xor(den2, 32); den3 += __shfl_xor(den3, 32);
    aA0 += __shfl_xor(aA0, 32);   aB0 += __shfl_xor(aB0, 32);
    aA1 += __shfl_xor(aA1, 32);   aB1 += __shfl_xor(aB1, 32);
    aA2 += __shfl_xor(aA2, 32);   aB2 += __shfl_xor(aB2, 32);
    aA3 += __shfl_xor(aA3, 32);   aB3 += __shfl_xor(aB3, 32);

    if (hw == 0) {
        f16* orow = &h1half[(size_t)n * 256];
        float i0 = 1.f / (den0 + 1e-16f);
        float i1 = 1.f / (den1 + 1e-16f);
        float i2 = 1.f / (den2 + 1e-16f);
        float i3 = 1.f / (den3 + 1e-16f);
        float2 bb0 = *(const float2*)&b1[0 * 64 + 2 * l];
        float2 bb1 = *(const float2*)&b1[1 * 64 + 2 * l];
        float2 bb2 = *(const float2*)&b1[2 * 64 + 2 * l];
        float2 bb3 = *(const float2*)&b1[3 * 64 + 2 * l];
        float rA, rB;
        rA = aA0 * i0 + bb0.x; rB = aB0 * i0 + bb0.y;
        *(f16x2*)&orow[0 * 64 + 2 * l] = f16x2{(f16)(rA > 0.f ? rA : 0.f), (f16)(rB > 0.f ? rB : 0.f)};
        rA = aA1 * i1 + bb1.x; rB = aB1 * i1 + bb1.y;
        *(f16x2*)&orow[1 * 64 + 2 * l] = f16x2{(f16)(rA > 0.f ? rA : 0.f), (f16)(rB > 0.f ? rB : 0.f)};
        rA = aA2 * i2 + bb2.x; rB = aB2 * i2 + bb2.y;
        *(f16x2*)&orow[2 * 64 + 2 * l] = f16x2{(f16)(rA > 0.f ? rA : 0.f), (f16)(rB > 0.f ? rB : 0.f)};
        rA = aA3 * i3 + bb3.x; rB = aB3 * i3 + bb3.y;
        *(f16x2*)&orow[3 * 64 + 2 * l] = f16x2{(f16)(rA > 0.f ? rA : 0.f), (f16)(rB > 0.f ? rB : 0.f)};
    }
}

// Layer-2 aggregation: same pairing; lane l covers channels 2l,2l+1 (f16x2).
__global__ __launch_bounds__(256)
void agg2_kernel(const int* __restrict__ offs, const int* __restrict__ csr_src,
                 const float* __restrict__ p2, const f16* __restrict__ h2linh,
                 const float* __restrict__ b2, f16* __restrict__ h2half) {
    int lane = threadIdx.x & 63;
    int hw = lane >> 5;
    int l = lane & 31;
    int n = blockIdx.x * 4 + (threadIdx.x >> 6);
    if (n >= NN) return;
    int beg = (n == 0) ? 0 : offs[n - 1];
    int end = offs[n];

    float den = 0.f, aA = 0.f, aB = 0.f;
    int j = beg + hw;
    for (; j + 6 < end; j += 8) {
        int s0 = csr_src[j + 0];
        int s1 = csr_src[j + 2];
        int s2 = csr_src[j + 4];
        int s3 = csr_src[j + 6];
        float q0 = p2[j + 0];
        float q1 = p2[j + 2];
        float q2 = p2[j + 4];
        float q3 = p2[j + 6];
        f16x2 v0 = *(const f16x2*)&h2linh[(size_t)s0 * 64 + l * 2];
        f16x2 v1 = *(const f16x2*)&h2linh[(size_t)s1 * 64 + l * 2];
        f16x2 v2 = *(const f16x2*)&h2linh[(size_t)s2 * 64 + l * 2];
        f16x2 v3 = *(const f16x2*)&h2linh[(size_t)s3 * 64 + l * 2];
        den += (q0 + q1) + (q2 + q3);
        aA += q0 * (float)v0[0] + q1 * (float)v1[0]
            + q2 * (float)v2[0] + q3 * (float)v3[0];
        aB += q0 * (float)v0[1] + q1 * (float)v1[1]
            + q2 * (float)v2[1] + q3 * (float)v3[1];
    }
    for (; j < end; j += 2) {
        int s = csr_src[j];
        float q = p2[j];
        f16x2 v = *(const f16x2*)&h2linh[(size_t)s * 64 + l * 2];
        den += q;
        aA += q * (float)v[0];
        aB += q * (float)v[1];
    }

    den += __shfl_xor(den, 32);
    aA  += __shfl_xor(aA, 32);
    aB  += __shfl_xor(aB, 32);

    if (hw == 0) {
        float inv = 1.f / (den + 1e-16f);
        float2 bb = *(const float2*)&b2[2 * l];
        f16x2 o = f16x2{(f16)(aA * inv + bb.x), (f16)(aB * inv + bb.y)};
        *(f16x2*)&h2half[(size_t)n * 64 + 2 * l] = o;
    }
}

// ---------------------------------------------------------------------------
// Edge epilogue: z = relu(g_top[p] + g_bot[c] + bm1); out = z @ Wm2 + bm2
// 16 lanes per edge; gh is fp16 [n][128].
// ---------------------------------------------------------------------------

__global__ __launch_bounds__(256)
void edge_kernel(const int* __restrict__ ei, const f16* __restrict__ gh,
                 const float* __restrict__ bm1, const float* __restrict__ Wm2,
                 const float* __restrict__ bm2, float* __restrict__ out) {
    int l = threadIdx.x & 15;
    int eid = blockIdx.x * 16 + (threadIdx.x >> 4);
    if (eid >= EE) return;
    int p = ei[eid];
    int c = ei[EE + eid];
    f16x4 av = *(const f16x4*)&gh[(size_t)p * 128 + l * 4];
    f16x4 bv = *(const f16x4*)&gh[(size_t)c * 128 + 64 + l * 4];
    float4 bb = *(const float4*)&bm1[l * 4];
    float zx = (float)av[0] + (float)bv[0] + bb.x; zx = zx > 0.f ? zx : 0.f;
    float zy = (float)av[1] + (float)bv[1] + bb.y; zy = zy > 0.f ? zy : 0.f;
    float zz = (float)av[2] + (float)bv[2] + bb.z; zz = zz > 0.f ? zz : 0.f;
    float zw = (float)av[3] + (float)bv[3] + bb.w; zw = zw > 0.f ? zw : 0.f;
    float4 w01 = *(const float4*)&Wm2[l * 8];       // rows 4l, 4l+1
    float4 w23 = *(const float4*)&Wm2[l * 8 + 4];   // rows 4l+2, 4l+3
    float o0 = zx * w01.x + zy * w01.z + zz * w23.x + zw * w23.z;
    float o1 = zx * w01.y + zy * w01.w + zz * w23.y + zw * w23.w;
#pragma unroll
    for (int m = 1; m < 16; m <<= 1) {
        o0 += __shfl_xor(o0, m);
        o1 += __shfl_xor(o1, m);
    }
    if (l == 0)
        *(float2*)&out[(size_t)eid * 2] = make_float2(o0 + bm2[0], o1 + bm2[1]);
}

// ---------------------------------------------------------------------------

extern "C" void kernel_launch(void* const* d_in, const int* in_sizes, int n_in,
                              void* d_out, int out_size, void* d_ws, size_t ws_size,
                              hipStream_t stream) {
    const float* x      = (const float*)d_in[0];
    const int*   ei     = (const int*)d_in[1];
    const float* W1     = (const float*)d_in[2];
    const float* a_src1 = (const float*)d_in[3];
    const float* a_dst1 = (const float*)d_in[4];
    const float* b1     = (const float*)d_in[5];
    const float* W2     = (const float*)d_in[6];
    const float* a_src2 = (const float*)d_in[7];
    const float* a_dst2 = (const float*)d_in[8];
    const float* b2     = (const float*)d_in[9];
    const float* Wm1    = (const float*)d_in[10];
    const float* bm1    = (const float*)d_in[11];
    const float* Wm2    = (const float*)d_in[12];
    const float* bm2    = (const float*)d_in[13];
    float* out = (float*)d_out;

    char* ws = (char*)d_ws;
    size_t off = 0;
    auto alloc = [&](size_t bytes) -> void* {
        void* p = ws + off;
        off += (bytes + 255) & ~(size_t)255;
        return p;
    };
    int*    deg     = (int*)alloc((size_t)NN * 4);
    int*    offs    = (int*)alloc((size_t)NN * 4);
    int*    bsum    = (int*)alloc(64 * 4);
    int*    bpre    = (int*)alloc(64 * 4);
    int*    csr_src = (int*)alloc((size_t)ENE * 4);
    int*    csr_dst = (int*)alloc((size_t)ENE * 4);
    float*  ss1     = (float*)alloc((size_t)NN * 4 * 4);
    float*  sd1     = (float*)alloc((size_t)NN * 4 * 4);
    float*  ss2     = (float*)alloc((size_t)NN * 4);
    float*  sd2     = (float*)alloc((size_t)NN * 4);
    float4* p1      = (float4*)alloc((size_t)ENE * 16);
    float*  p2      = (float*)alloc((size_t)ENE * 4);
    f16*    W1t     = (f16*)alloc((size_t)256 * 128 * 2);
    f16*    W2t     = (f16*)alloc((size_t)64 * 256 * 2);
    f16*    Wmt     = (f16*)alloc((size_t)128 * 64 * 2);
    f16*    h1h     = (f16*)alloc((size_t)NN * 256 * 2);   // permuted [n][c][h]
    f16*    h1half  = (f16*)alloc((size_t)NN * 256 * 2);   // [n][h*64+c]
    f16*    h2linh  = (f16*)alloc((size_t)NN * 64 * 2);
    f16*    h2half  = (f16*)alloc((size_t)NN * 64 * 2);
    f16*    gh      = (f16*)alloc((size_t)NN * 128 * 2);
    if (off > ws_size) return;   // insufficient workspace: leave output poisoned

    const int nbScan  = (NN + 1023) / 1024;        // 49
    const int gEdges  = (ENE + 255) / 256;         // 3321
    const int gNodes4 = (NN + 3) / 4;              // 12500
    const int gEdge16 = (EE + 15) / 16;            // 50000

    // Weight casts (independent of CSR)
    cast_w_kernel<<<(57344 + 255) / 256, 256, 0, stream>>>(W1, W2, Wm1, W1t, W2t, Wmt);

    // CSR degree + scan (independent of gemm1)
    hipMemsetAsync(deg, 0, (size_t)NN * 4, stream);
    deg_kernel<<<gEdges, 256, 0, stream>>>(ei, deg);
    scan1_kernel<<<nbScan, 1024, 0, stream>>>(deg, offs, bsum);
    scan2_kernel<<<1, 64, 0, stream>>>(bsum, bpre, nbScan);
    scan3_kernel<<<(NN + 255) / 256, 256, 0, stream>>>(offs, bpre);

    // Layer 1 linear + fused scores
    mfma_gemm<128, 256, 1, 4, 1, 1, 1><<<NN / 16, 256, 0, stream>>>(
        x, W1t, h1h, a_src1, a_dst1, ss1, sd1, NN);

    // Scatter + fused p1 (needs ss1/sd1)
    scatter_p1_kernel<<<gEdges, 256, 0, stream>>>(ei, offs, csr_src, csr_dst,
                                                  ss1, sd1, p1);
    agg1_kernel<<<gNodes4, 256, 0, stream>>>(offs, csr_src, p1, h1h, b1, h1half);

    // Layer 2: h2lin = h1 @ W2 (+ fused scores)
    mfma_gemm<256, 64, 4, 1, 0, 0, 2><<<(NN + 63) / 64, 256, 0, stream>>>(
        h1half, W2t, h2linh, a_src2, a_dst2, ss2, sd2, NN);
    p2_kernel<<<gEdges, 256, 0, stream>>>(csr_src, csr_dst, ss2, sd2, p2);
    agg2_kernel<<<gNodes4, 256, 0, stream>>>(offs, csr_src, p2, h2linh, b2, h2half);

    // Edge MLP (factorized): gh = h2 @ [Wm1_top | Wm1_bot], per-edge epilogue
    mfma_gemm<64, 128, 2, 2, 0, 0, 0><<<(NN + 31) / 32, 256, 0, stream>>>(
        h2half, Wmt, gh, nullptr, nullptr, nullptr, nullptr, NN);
    edge_kernel<<<gEdge16, 256, 0, stream>>>(ei, gh, bm1, Wm2, bm2, out);
}

// Round 11
// 392.808 us; speedup vs baseline: 1.1220x; 1.0356x over previous
//
#include <hip/hip_runtime.h>
#include <hip/hip_fp16.h>

#define NN 50000
#define EE 800000
#define ENE (EE + NN)   // edges + self loops

typedef _Float16 f16;
typedef __attribute__((ext_vector_type(8))) _Float16 f16x8;
typedef __attribute__((ext_vector_type(4))) _Float16 f16x4;
typedef __attribute__((ext_vector_type(2))) _Float16 f16x2;
typedef __attribute__((ext_vector_type(4))) float f32x4;

// ---------------------------------------------------------------------------
// CSR build: degree count -> exclusive scan -> scatter (bump allocator).
// After scatter, offs[n] = end of segment n; beg(n) = n ? offs[n-1] : 0.
// ---------------------------------------------------------------------------

__global__ __launch_bounds__(256)
void deg_kernel(const int* __restrict__ ei, int* __restrict__ deg) {
    int i = blockIdx.x * 256 + threadIdx.x;
    if (i >= ENE) return;
    int d = (i < EE) ? ei[EE + i] : (i - EE);   // dst row of edge_index
    atomicAdd(&deg[d], 1);
}

__global__ __launch_bounds__(1024)
void scan1_kernel(const int* __restrict__ deg, int* __restrict__ offs,
                  int* __restrict__ bsum) {
    __shared__ int s[1024];
    int t = threadIdx.x;
    int i = blockIdx.x * 1024 + t;
    int v = (i < NN) ? deg[i] : 0;
    s[t] = v;
    __syncthreads();
    for (int off = 1; off < 1024; off <<= 1) {
        int a = (t >= off) ? s[t - off] : 0;
        __syncthreads();
        s[t] += a;
        __syncthreads();
    }
    if (i < NN) offs[i] = s[t] - v;   // exclusive
    if (t == 1023) bsum[blockIdx.x] = s[1023];
}

__global__ __launch_bounds__(64)
void scan2_kernel(const int* __restrict__ bsum, int* __restrict__ bpre, int nb) {
    if (threadIdx.x == 0) {
        int run = 0;
        for (int b = 0; b < nb; ++b) { bpre[b] = run; run += bsum[b]; }
    }
}

__global__ __launch_bounds__(256)
void scan3_kernel(int* __restrict__ offs, const int* __restrict__ bpre) {
    int i = blockIdx.x * 256 + threadIdx.x;
    if (i >= NN) return;
    offs[i] += bpre[i >> 10];
}

// Scatter + fused layer-1 edge weights: p1[slot] = exp(leaky(ss1[s]+sd1[d])).
// Runs after gemm1 (needs ss1/sd1). csr_dst no longer materialized.
__global__ __launch_bounds__(256)
void scatter_p1_kernel(const int* __restrict__ ei, int* __restrict__ offs,
                       int* __restrict__ csr_src,
                       const float* __restrict__ ss, const float* __restrict__ sd,
                       float4* __restrict__ p1) {
    int i = blockIdx.x * 256 + threadIdx.x;
    if (i >= ENE) return;
    int d, s;
    if (i < EE) { s = ei[i]; d = ei[EE + i]; }
    else        { s = i - EE; d = i - EE; }
    int slot = atomicAdd(&offs[d], 1);
    csr_src[slot] = s;
    float4 a = *(const float4*)&ss[s * 4];
    float4 b = *(const float4*)&sd[d * 4];
    float e0 = a.x + b.x; e0 = e0 > 0.f ? e0 : 0.2f * e0;
    float e1 = a.y + b.y; e1 = e1 > 0.f ? e1 : 0.2f * e1;
    float e2 = a.z + b.z; e2 = e2 > 0.f ? e2 : 0.2f * e2;
    float e3 = a.w + b.w; e3 = e3 > 0.f ? e3 : 0.2f * e3;
    p1[slot] = make_float4(__expf(e0), __expf(e1), __expf(e2), __expf(e3));
}

// ---------------------------------------------------------------------------
// fp32 weights -> transposed fp16 copies (MFMA B-fragments = contiguous 16B).
// ---------------------------------------------------------------------------

__global__ __launch_bounds__(256)
void cast_w_kernel(const float* __restrict__ W1, const float* __restrict__ W2,
                   const float* __restrict__ Wm1, f16* __restrict__ W1t,
                   f16* __restrict__ W2t, f16* __restrict__ Wmt) {
    int idx = blockIdx.x * 256 + threadIdx.x;
    if (idx < 32768) {                       // W1t[j*128+k] = W1[k*256+j]
        int j = idx >> 7, k = idx & 127;
        W1t[idx] = (f16)W1[k * 256 + j];
    } else if (idx < 49152) {                // W2t[j*256+k] = W2[k*64+j]
        int i = idx - 32768;
        int j = i >> 8, k = i & 255;
        W2t[i] = (f16)W2[k * 64 + j];
    } else if (idx < 57344) {                // Wmt[j*64+k]
        int i = idx - 49152;
        int j = i >> 6, k = i & 63;
        float v = (j < 64) ? Wm1[k * 64 + j] : Wm1[(64 + k) * 64 + (j - 64)];
        Wmt[i] = (f16)v;
    }
}

// ---------------------------------------------------------------------------
// MFMA fp16 GEMM: Yh[n, NOUT] = A[n, K] @ Bt^T   (Bt is [NOUT][K] fp16)
// 4 waves/block; wave (wr,wc) computes 16 rows x 64 cols via 4x
// v_mfma_f32_16x16x32_f16 per k-step, register-direct fragments.
// PERM=1: permuted [n][c(64)][h(4)] output layout.
// AF32=1: A is fp32, converted in-register.
// SCORES=1: fused layer-1 attention scores. SCORES=2: fused layer-2 scores.
// ---------------------------------------------------------------------------

template<int K, int NOUT, int NWR, int NWC, int PERM, int AF32, int SCORES>
__global__ __launch_bounds__(256)
void mfma_gemm(const void* __restrict__ Avoid, const f16* __restrict__ Bt,
               f16* __restrict__ Yh, const float* __restrict__ a_src,
               const float* __restrict__ a_dst, float* __restrict__ ss,
               float* __restrict__ sd, int nrows) {
    constexpr int BROWS = NWR * 16;
    constexpr int LDP = NOUT + 8;            // halves per LDS row (16B pad)
    __shared__ f16 lds[BROWS * LDP];
    const int tid = threadIdx.x;
    const int wid = tid >> 6, lane = tid & 63;
    const int wr = wid / NWC, wc = wid % NWC;
    const int lm = lane & 15, lk = lane >> 4;      // lk in 0..3
    const int row0 = blockIdx.x * BROWS + wr * 16;
    const int col0 = wc * 64;

    const float* A32 = (const float*)Avoid;
    const f16*   A16 = (const f16*)Avoid;

    int arow = row0 + lm;
    if (arow >= nrows) arow = nrows - 1;           // clamp (partial last block)

    f32x4 acc[4] = {};
#pragma unroll
    for (int ks = 0; ks < K / 32; ++ks) {
        f16x8 af;
        if (AF32) {
            float4 v0 = *(const float4*)&A32[(size_t)arow * K + ks * 32 + lk * 8];
            float4 v1 = *(const float4*)&A32[(size_t)arow * K + ks * 32 + lk * 8 + 4];
            af = f16x8{(f16)v0.x, (f16)v0.y, (f16)v0.z, (f16)v0.w,
                       (f16)v1.x, (f16)v1.y, (f16)v1.z, (f16)v1.w};
        } else {
            af = *(const f16x8*)(A16 + (size_t)arow * K + ks * 32 + lk * 8);
        }
#pragma unroll
        for (int ct = 0; ct < 4; ++ct) {
            const f16* bptr = Bt + (size_t)(col0 + ct * 16 + lm) * K + ks * 32 + lk * 8;
            f16x8 bf = *(const f16x8*)bptr;
            acc[ct] = __builtin_amdgcn_mfma_f32_16x16x32_f16(af, bf, acc[ct], 0, 0, 0);
        }
    }

    // C/D frag: col = lane&15, row = (lane>>4)*4 + r  [m89 layout]
#pragma unroll
    for (int ct = 0; ct < 4; ++ct) {
#pragma unroll
        for (int r = 0; r < 4; ++r) {
            int lrow = wr * 16 + lk * 4 + r;       // local row in block
            int j = col0 + ct * 16 + lm;           // global col
            int jj = PERM ? ((j & 63) * 4 + (j >> 6)) : j;
            lds[lrow * LDP + jj] = (f16)acc[ct][r];
        }
    }
    __syncthreads();

    constexpr int CHUNKS = NOUT / 8;               // 16B chunks per row
    for (int idx = tid; idx < BROWS * CHUNKS; idx += 256) {
        int lrow = idx / CHUNKS, ch = idx % CHUNKS;
        int grow = blockIdx.x * BROWS + lrow;
        if (grow < nrows) {
            f16x8 v = *(const f16x8*)&lds[lrow * LDP + ch * 8];
            *(f16x8*)&Yh[(size_t)grow * NOUT + ch * 8] = v;
        }
    }

    if (SCORES == 1) {
        // layer-1: ss[n][h] = sum_c h[n,h,c]*a_src[h,c]; lds is [16][c*4+h].
        int rloc = wid * 4 + (lane >> 4);
        int ci = lane & 15;
        float ps[4] = {}, pd[4] = {};
#pragma unroll
        for (int cc = 0; cc < 4; ++cc) {
            int c = ci + cc * 16;
            f16x4 hv = *(const f16x4*)&lds[rloc * LDP + c * 4];
#pragma unroll
            for (int h = 0; h < 4; ++h) {
                float f = (float)hv[h];
                ps[h] += f * a_src[h * 64 + c];
                pd[h] += f * a_dst[h * 64 + c];
            }
        }
#pragma unroll
        for (int m = 1; m < 16; m <<= 1) {
#pragma unroll
            for (int h = 0; h < 4; ++h) {
                ps[h] += __shfl_xor(ps[h], m);
                pd[h] += __shfl_xor(pd[h], m);
            }
        }
        if (ci == 0) {
            int grow = blockIdx.x * BROWS + rloc;
            if (grow < nrows) {
                *(float4*)&ss[grow * 4] = make_float4(ps[0], ps[1], ps[2], ps[3]);
                *(float4*)&sd[grow * 4] = make_float4(pd[0], pd[1], pd[2], pd[3]);
            }
        }
    } else if (SCORES == 2) {
        // layer-2: ss[n] = sum_c h2[n,c]*a_src[c]; 4 lanes/row, 16 c's each.
        int rloc = wid * 16 + (lane >> 2);
        int cg = lane & 3;
        float ps = 0.f, pd = 0.f;
#pragma unroll
        for (int b = 0; b < 2; ++b) {
            f16x8 hv = *(const f16x8*)&lds[rloc * LDP + cg * 16 + b * 8];
#pragma unroll
            for (int u = 0; u < 8; ++u) {
                int c = cg * 16 + b * 8 + u;
                float f = (float)hv[u];
                ps += f * a_src[c];
                pd += f * a_dst[c];
            }
        }
        ps += __shfl_xor(ps, 1); ps += __shfl_xor(ps, 2);
        pd += __shfl_xor(pd, 1); pd += __shfl_xor(pd, 2);
        if (cg == 0) {
            int grow = blockIdx.x * BROWS + rloc;
            if (grow < nrows) { ss[grow] = ps; sd[grow] = pd; }
        }
    }
}

// ---------------------------------------------------------------------------
// Layer-1 aggregation: ONE wave per dst node; intra-wave edge PAIRING:
// lanes 0-31 take even CSR slots, lanes 32-63 odd slots. Lane l covers
// channels 2l,2l+1 x 4 heads via one 16B load. shfl_xor(...,32) combine.
// ---------------------------------------------------------------------------

__global__ __launch_bounds__(256)
void agg1_kernel(const int* __restrict__ offs, const int* __restrict__ csr_src,
                 const float4* __restrict__ p1, const f16* __restrict__ h1h,
                 const float* __restrict__ b1, f16* __restrict__ h1half) {
    int lane = threadIdx.x & 63;
    int hw = lane >> 5;         // which edge of the pair
    int l = lane & 31;          // channel pair index
    int n = blockIdx.x * 4 + (threadIdx.x >> 6);
    if (n >= NN) return;
    int beg = (n == 0) ? 0 : offs[n - 1];
    int end = offs[n];

    float den0 = 0.f, den1 = 0.f, den2 = 0.f, den3 = 0.f;
    float aA0 = 0.f, aA1 = 0.f, aA2 = 0.f, aA3 = 0.f;   // channel 2l
    float aB0 = 0.f, aB1 = 0.f, aB2 = 0.f, aB3 = 0.f;   // channel 2l+1
    int j = beg + hw;           // stride-2 walk per half

#define AGG1_BODY(JJ)                                                          \
    {                                                                          \
        int s_ = csr_src[JJ];                                                  \
        float4 q_ = p1[JJ];                                                    \
        f16x8 hv_ = *(const f16x8*)&h1h[(size_t)s_ * 256 + l * 8];             \
        den0 += q_.x; den1 += q_.y; den2 += q_.z; den3 += q_.w;                \
        aA0 += q_.x * (float)hv_[0]; aB0 += q_.x * (float)hv_[4];              \
        aA1 += q_.y * (float)hv_[1]; aB1 += q_.y * (float)hv_[5];              \
        aA2 += q_.z * (float)hv_[2]; aB2 += q_.z * (float)hv_[6];              \
        aA3 += q_.w * (float)hv_[3]; aB3 += q_.w * (float)hv_[7];              \
    }

    for (; j + 6 < end; j += 8) {
        int s0 = csr_src[j + 0];
        int s1 = csr_src[j + 2];
        int s2 = csr_src[j + 4];
        int s3 = csr_src[j + 6];
        float4 q0 = p1[j + 0];
        float4 q1 = p1[j + 2];
        float4 q2 = p1[j + 4];
        float4 q3 = p1[j + 6];
        f16x8 h0 = *(const f16x8*)&h1h[(size_t)s0 * 256 + l * 8];
        f16x8 h1v = *(const f16x8*)&h1h[(size_t)s1 * 256 + l * 8];
        f16x8 h2v = *(const f16x8*)&h1h[(size_t)s2 * 256 + l * 8];
        f16x8 h3v = *(const f16x8*)&h1h[(size_t)s3 * 256 + l * 8];
        den0 += (q0.x + q1.x) + (q2.x + q3.x);
        den1 += (q0.y + q1.y) + (q2.y + q3.y);
        den2 += (q0.z + q1.z) + (q2.z + q3.z);
        den3 += (q0.w + q1.w) + (q2.w + q3.w);
        aA0 += q0.x * (float)h0[0] + q1.x * (float)h1v[0]
             + q2.x * (float)h2v[0] + q3.x * (float)h3v[0];
        aB0 += q0.x * (float)h0[4] + q1.x * (float)h1v[4]
             + q2.x * (float)h2v[4] + q3.x * (float)h3v[4];
        aA1 += q0.y * (float)h0[1] + q1.y * (float)h1v[1]
             + q2.y * (float)h2v[1] + q3.y * (float)h3v[1];
        aB1 += q0.y * (float)h0[5] + q1.y * (float)h1v[5]
             + q2.y * (float)h2v[5] + q3.y * (float)h3v[5];
        aA2 += q0.z * (float)h0[2] + q1.z * (float)h1v[2]
             + q2.z * (float)h2v[2] + q3.z * (float)h3v[2];
        aB2 += q0.z * (float)h0[6] + q1.z * (float)h1v[6]
             + q2.z * (float)h2v[6] + q3.z * (float)h3v[6];
        aA3 += q0.w * (float)h0[3] + q1.w * (float)h1v[3]
             + q2.w * (float)h2v[3] + q3.w * (float)h3v[3];
        aB3 += q0.w * (float)h0[7] + q1.w * (float)h1v[7]
             + q2.w * (float)h2v[7] + q3.w * (float)h3v[7];
    }
    for (; j < end; j += 2) AGG1_BODY(j);
#undef AGG1_BODY

    // combine the two halves (edge-pair partials)
    den0 += __shfl_xor(den0, 32); den1 += __shfl_xor(den1, 32);
    den2 += __shfl_xor(den2, 32); den3 += __shfl_xor(den3, 32);
    aA0 += __shfl_xor(aA0, 32);   aB0 += __shfl_xor(aB0, 32);
    aA1 += __shfl_xor(aA1, 32);   aB1 += __shfl_xor(aB1, 32);
    aA2 += __shfl_xor(aA2, 32);   aB2 += __shfl_xor(aB2, 32);
    aA3 += __shfl_xor(aA3, 32);   aB3 += __shfl_xor(aB3, 32);

    if (hw == 0) {
        f16* orow = &h1half[(size_t)n * 256];
        float i0 = 1.f / (den0 + 1e-16f);
        float i1 = 1.f / (den1 + 1e-16f);
        float i2 = 1.f / (den2 + 1e-16f);
        float i3 = 1.f / (den3 + 1e-16f);
        float2 bb0 = *(const float2*)&b1[0 * 64 + 2 * l];
        float2 bb1 = *(const float2*)&b1[1 * 64 + 2 * l];
        float2 bb2 = *(const float2*)&b1[2 * 64 + 2 * l];
        float2 bb3 = *(const float2*)&b1[3 * 64 + 2 * l];
        float rA, rB;
        rA = aA0 * i0 + bb0.x; rB = aB0 * i0 + bb0.y;
        *(f16x2*)&orow[0 * 64 + 2 * l] = f16x2{(f16)(rA > 0.f ? rA : 0.f), (f16)(rB > 0.f ? rB : 0.f)};
        rA = aA1 * i1 + bb1.x; rB = aB1 * i1 + bb1.y;
        *(f16x2*)&orow[1 * 64 + 2 * l] = f16x2{(f16)(rA > 0.f ? rA : 0.f), (f16)(rB > 0.f ? rB : 0.f)};
        rA = aA2 * i2 + bb2.x; rB = aB2 * i2 + bb2.y;
        *(f16x2*)&orow[2 * 64 + 2 * l] = f16x2{(f16)(rA > 0.f ? rA : 0.f), (f16)(rB > 0.f ? rB : 0.f)};
        rA = aA3 * i3 + bb3.x; rB = aB3 * i3 + bb3.y;
        *(f16x2*)&orow[3 * 64 + 2 * l] = f16x2{(f16)(rA > 0.f ? rA : 0.f), (f16)(rB > 0.f ? rB : 0.f)};
    }
}

// Layer-2 aggregation: same pairing; p2 computed INLINE (ss2 gather + exp),
// killing the separate p2 kernel and csr_dst. sd2[n] is wave-uniform.
__global__ __launch_bounds__(256)
void agg2_kernel(const int* __restrict__ offs, const int* __restrict__ csr_src,
                 const float* __restrict__ ss, const float* __restrict__ sd,
                 const f16* __restrict__ h2linh,
                 const float* __restrict__ b2, f16* __restrict__ h2half) {
    int lane = threadIdx.x & 63;
    int hw = lane >> 5;
    int l = lane & 31;
    int n = blockIdx.x * 4 + (threadIdx.x >> 6);
    if (n >= NN) return;
    int beg = (n == 0) ? 0 : offs[n - 1];
    int end = offs[n];
    float sdn = sd[n];

    float den = 0.f, aA = 0.f, aB = 0.f;
    int j = beg + hw;
    for (; j + 6 < end; j += 8) {
        int s0 = csr_src[j + 0];
        int s1 = csr_src[j + 2];
        int s2 = csr_src[j + 4];
        int s3 = csr_src[j + 6];
        float e0 = ss[s0] + sdn;
        float e1 = ss[s1] + sdn;
        float e2 = ss[s2] + sdn;
        float e3 = ss[s3] + sdn;
        f16x2 v0 = *(const f16x2*)&h2linh[(size_t)s0 * 64 + l * 2];
        f16x2 v1 = *(const f16x2*)&h2linh[(size_t)s1 * 64 + l * 2];
        f16x2 v2 = *(const f16x2*)&h2linh[(size_t)s2 * 64 + l * 2];
        f16x2 v3 = *(const f16x2*)&h2linh[(size_t)s3 * 64 + l * 2];
        e0 = e0 > 0.f ? e0 : 0.2f * e0;
        e1 = e1 > 0.f ? e1 : 0.2f * e1;
        e2 = e2 > 0.f ? e2 : 0.2f * e2;
        e3 = e3 > 0.f ? e3 : 0.2f * e3;
        float q0 = __expf(e0);
        float q1 = __expf(e1);
        float q2 = __expf(e2);
        float q3 = __expf(e3);
        den += (q0 + q1) + (q2 + q3);
        aA += q0 * (float)v0[0] + q1 * (float)v1[0]
            + q2 * (float)v2[0] + q3 * (float)v3[0];
        aB += q0 * (float)v0[1] + q1 * (float)v1[1]
            + q2 * (float)v2[1] + q3 * (float)v3[1];
    }
    for (; j < end; j += 2) {
        int s = csr_src[j];
        float e = ss[s] + sdn;
        e = e > 0.f ? e : 0.2f * e;
        float q = __expf(e);
        f16x2 v = *(const f16x2*)&h2linh[(size_t)s * 64 + l * 2];
        den += q;
        aA += q * (float)v[0];
        aB += q * (float)v[1];
    }

    den += __shfl_xor(den, 32);
    aA  += __shfl_xor(aA, 32);
    aB  += __shfl_xor(aB, 32);

    if (hw == 0) {
        float inv = 1.f / (den + 1e-16f);
        float2 bb = *(const float2*)&b2[2 * l];
        f16x2 o = f16x2{(f16)(aA * inv + bb.x), (f16)(aB * inv + bb.y)};
        *(f16x2*)&h2half[(size_t)n * 64 + 2 * l] = o;
    }
}

// ---------------------------------------------------------------------------
// Edge epilogue: z = relu(g_top[p] + g_bot[c] + bm1); out = z @ Wm2 + bm2
// 8 lanes per edge (f16x8 16B loads) -> 8 edges in flight per wave.
// ---------------------------------------------------------------------------

__global__ __launch_bounds__(256)
void edge_kernel(const int* __restrict__ ei, const f16* __restrict__ gh,
                 const float* __restrict__ bm1, const float* __restrict__ Wm2,
                 const float* __restrict__ bm2, float* __restrict__ out) {
    int l = threadIdx.x & 7;
    int eid = blockIdx.x * 32 + (threadIdx.x >> 3);
    if (eid >= EE) return;
    int p = ei[eid];
    int c = ei[EE + eid];
    f16x8 av = *(const f16x8*)&gh[(size_t)p * 128 + l * 8];
    f16x8 bv = *(const f16x8*)&gh[(size_t)c * 128 + 64 + l * 8];
    float4 bb0 = *(const float4*)&bm1[l * 8];
    float4 bb1 = *(const float4*)&bm1[l * 8 + 4];
    float z0 = (float)av[0] + (float)bv[0] + bb0.x; z0 = z0 > 0.f ? z0 : 0.f;
    float z1 = (float)av[1] + (float)bv[1] + bb0.y; z1 = z1 > 0.f ? z1 : 0.f;
    float z2 = (float)av[2] + (float)bv[2] + bb0.z; z2 = z2 > 0.f ? z2 : 0.f;
    float z3 = (float)av[3] + (float)bv[3] + bb0.w; z3 = z3 > 0.f ? z3 : 0.f;
    float z4 = (float)av[4] + (float)bv[4] + bb1.x; z4 = z4 > 0.f ? z4 : 0.f;
    float z5 = (float)av[5] + (float)bv[5] + bb1.y; z5 = z5 > 0.f ? z5 : 0.f;
    float z6 = (float)av[6] + (float)bv[6] + bb1.z; z6 = z6 > 0.f ? z6 : 0.f;
    float z7 = (float)av[7] + (float)bv[7] + bb1.w; z7 = z7 > 0.f ? z7 : 0.f;
    // Wm2 rows 8l..8l+7, 2 cols: packed pairs {row k: [2k]=col0, [2k+1]=col1}
    float4 w01 = *(const float4*)&Wm2[l * 16];
    float4 w23 = *(const float4*)&Wm2[l * 16 + 4];
    float4 w45 = *(const float4*)&Wm2[l * 16 + 8];
    float4 w67 = *(const float4*)&Wm2[l * 16 + 12];
    float o0 = z0 * w01.x + z1 * w01.z + z2 * w23.x + z3 * w23.z
             + z4 * w45.x + z5 * w45.z + z6 * w67.x + z7 * w67.z;
    float o1 = z0 * w01.y + z1 * w01.w + z2 * w23.y + z3 * w23.w
             + z4 * w45.y + z5 * w45.w + z6 * w67.y + z7 * w67.w;
#pragma unroll
    for (int m = 1; m < 8; m <<= 1) {
        o0 += __shfl_xor(o0, m);
        o1 += __shfl_xor(o1, m);
    }
    if (l == 0)
        *(float2*)&out[(size_t)eid * 2] = make_float2(o0 + bm2[0], o1 + bm2[1]);
}

// ---------------------------------------------------------------------------

extern "C" void kernel_launch(void* const* d_in, const int* in_sizes, int n_in,
                              void* d_out, int out_size, void* d_ws, size_t ws_size,
                              hipStream_t stream) {
    const float* x      = (const float*)d_in[0];
    const int*   ei     = (const int*)d_in[1];
    const float* W1     = (const float*)d_in[2];
    const float* a_src1 = (const float*)d_in[3];
    const float* a_dst1 = (const float*)d_in[4];
    const float* b1     = (const float*)d_in[5];
    const float* W2     = (const float*)d_in[6];
    const float* a_src2 = (const float*)d_in[7];
    const float* a_dst2 = (const float*)d_in[8];
    const float* b2     = (const float*)d_in[9];
    const float* Wm1    = (const float*)d_in[10];
    const float* bm1    = (const float*)d_in[11];
    const float* Wm2    = (const float*)d_in[12];
    const float* bm2    = (const float*)d_in[13];
    float* out = (float*)d_out;

    char* ws = (char*)d_ws;
    size_t off = 0;
    auto alloc = [&](size_t bytes) -> void* {
        void* p = ws + off;
        off += (bytes + 255) & ~(size_t)255;
        return p;
    };
    int*    deg     = (int*)alloc((size_t)NN * 4);
    int*    offs    = (int*)alloc((size_t)NN * 4);
    int*    bsum    = (int*)alloc(64 * 4);
    int*    bpre    = (int*)alloc(64 * 4);
    int*    csr_src = (int*)alloc((size_t)ENE * 4);
    float*  ss1     = (float*)alloc((size_t)NN * 4 * 4);
    float*  sd1     = (float*)alloc((size_t)NN * 4 * 4);
    float*  ss2     = (float*)alloc((size_t)NN * 4);
    float*  sd2     = (float*)alloc((size_t)NN * 4);
    float4* p1      = (float4*)alloc((size_t)ENE * 16);
    f16*    W1t     = (f16*)alloc((size_t)256 * 128 * 2);
    f16*    W2t     = (f16*)alloc((size_t)64 * 256 * 2);
    f16*    Wmt     = (f16*)alloc((size_t)128 * 64 * 2);
    f16*    h1h     = (f16*)alloc((size_t)NN * 256 * 2);   // permuted [n][c][h]
    f16*    h1half  = (f16*)alloc((size_t)NN * 256 * 2);   // [n][h*64+c]
    f16*    h2linh  = (f16*)alloc((size_t)NN * 64 * 2);
    f16*    h2half  = (f16*)alloc((size_t)NN * 64 * 2);
    f16*    gh      = (f16*)alloc((size_t)NN * 128 * 2);
    if (off > ws_size) return;   // insufficient workspace: leave output poisoned

    const int nbScan  = (NN + 1023) / 1024;        // 49
    const int gEdges  = (ENE + 255) / 256;         // 3321
    const int gNodes4 = (NN + 3) / 4;              // 12500
    const int gEdge32 = (EE + 31) / 32;            // 25000

    // Weight casts (independent of CSR)
    cast_w_kernel<<<(57344 + 255) / 256, 256, 0, stream>>>(W1, W2, Wm1, W1t, W2t, Wmt);

    // CSR degree + scan (independent of gemm1)
    hipMemsetAsync(deg, 0, (size_t)NN * 4, stream);
    deg_kernel<<<gEdges, 256, 0, stream>>>(ei, deg);
    scan1_kernel<<<nbScan, 1024, 0, stream>>>(deg, offs, bsum);
    scan2_kernel<<<1, 64, 0, stream>>>(bsum, bpre, nbScan);
    scan3_kernel<<<(NN + 255) / 256, 256, 0, stream>>>(offs, bpre);

    // Layer 1 linear + fused scores
    mfma_gemm<128, 256, 1, 4, 1, 1, 1><<<NN / 16, 256, 0, stream>>>(
        x, W1t, h1h, a_src1, a_dst1, ss1, sd1, NN);

    // Scatter + fused p1 (needs ss1/sd1)
    scatter_p1_kernel<<<gEdges, 256, 0, stream>>>(ei, offs, csr_src, ss1, sd1, p1);
    agg1_kernel<<<gNodes4, 256, 0, stream>>>(offs, csr_src, p1, h1h, b1, h1half);

    // Layer 2: h2lin = h1 @ W2 (+ fused scores); p2 computed inline in agg2
    mfma_gemm<256, 64, 4, 1, 0, 0, 2><<<(NN + 63) / 64, 256, 0, stream>>>(
        h1half, W2t, h2linh, a_src2, a_dst2, ss2, sd2, NN);
    agg2_kernel<<<gNodes4, 256, 0, stream>>>(offs, csr_src, ss2, sd2, h2linh, b2, h2half);

    // Edge MLP (factorized): gh = h2 @ [Wm1_top | Wm1_bot], per-edge epilogue
    mfma_gemm<64, 128, 2, 2, 0, 0, 0><<<(NN + 31) / 32, 256, 0, stream>>>(
        h2half, Wmt, gh, nullptr, nullptr, nullptr, nullptr, NN);
    edge_kernel<<<gEdge32, 256, 0, stream>>>(ei, gh, bm1, Wm2, bm2, out);
}